// Round 4
// baseline (372.992 us; speedup 1.0000x reference)
//
#include <hip/hip_runtime.h>

// DifferentiableTMO: per-batch piecewise-linear CRF LUT over 8x3x1080x1920 fp32.
// HBM floor: 199MB read + 199MB write ~= 63us @6.3TB/s (measured copy ceiling).
// R5: PARTITION DIAGNOSTIC. R3 (LDS-chain removal) and R4 (source-level
//     load/store reorder; compiler re-sank it, VGPR=28) were both neutral at
//     ~132us with no pipe >30%. Three dispatches on one stream (serialized,
//     per-dispatch rocprof rows via distinct names), all correct:
//       tmo_ctrl_nt2048  b0-2: R4 control (NT stores, M=2048)
//       tmo_plain2048    b3-5: plain stores        -> tests vmcnt/NT-retire coupling
//       tmo_nt1024       b6-7: M=1024 (11.2KB LDS) -> tests occupancy/LDS-granule cap

#define KS 256          // CRF sample points
#define NB 25           // PCA basis curves
#define NPIX_PER_B 6220800            // 3*1080*1920
#define NP4 (NPIX_PER_B / 4)          // 1555200 float4 per batch

#define SENTINEL 0xFFFFFFFFu          // negative NaN; real slopes are finite

typedef float nvec4 __attribute__((ext_vector_type(4)));

template<bool NT>
__device__ __forceinline__ void store4(float4* dst, float4 v)
{
    if (NT) __builtin_nontemporal_store(*(const nvec4*)&v, (nvec4*)dst);
    else    *dst = v;
}

template<int MB>
__device__ __forceinline__ float interp_one(float x,
                                            const float* __restrict__ sE,
                                            const float2* __restrict__ sSeg,
                                            const float2* __restrict__ sBin)
{
    int m = (int)(x * (float)MB);      // x in [0,1): exponent shift, exact
    m = (m > MB - 1) ? (MB - 1) : m;
    float2 sg = sBin[m];               // single ds_read_b64 common path
    if (__builtin_expect(__float_as_uint(sg.x) == SENTINEL, 0)) {
        unsigned int pk = __float_as_uint(sg.y);
        unsigned int j  = pk & 0x1FFu;     // upper_bound(E, bin_start)
        unsigned int c  = pk >> 9;         // breakpoints inside this bin
        while (c) {
            if (sE[j] > x) break;
            ++j; --c;
        }
        sg = sSeg[j];
    }
    float y = fmaf(sg.x, x, sg.y);
    return fminf(fmaxf(y, 0.0f), 1.0f);
}

template<int MB, bool NT>
__device__ __forceinline__ float4 interp_vec(float4 p,
                                             const float* __restrict__ sE,
                                             const float2* __restrict__ sSeg,
                                             const float2* __restrict__ sBin)
{
    float4 r;
    r.x = interp_one<MB>(p.x, sE, sSeg, sBin);
    r.y = interp_one<MB>(p.y, sE, sSeg, sBin);
    r.z = interp_one<MB>(p.z, sE, sSeg, sBin);
    r.w = interp_one<MB>(p.w, sE, sSeg, sBin);
    return r;
}

template<int MB, bool NT>
__device__ __forceinline__ void tmo_body(const float* __restrict__ hdr,
                                         const float* __restrict__ w,
                                         const float* __restrict__ E,
                                         const float* __restrict__ f0,
                                         const float* __restrict__ Hb,
                                         float* __restrict__ out)
{
    __shared__ float  sE[KS];                     // 1 KB
    __shared__ float2 sSeg[KS + 1];               // 2056 B
    __shared__ float2 sBin[MB];                   // 8*MB bytes

    float* sC = (float*)sBin;                     // overlay: dead after sSeg built

    const int tid = threadIdx.x;
    const int b   = blockIdx.y;

    // ---- stage E, per-batch curve ----
    sE[tid] = E[tid];
    {
        float acc = f0[tid];
        const float* wb = w + b * NB;   // block-uniform -> scalar loads
        const float* hb = Hb + tid * NB;
        #pragma unroll
        for (int n = 0; n < NB; ++n) acc = fmaf(hb[n], wb[n], acc);
        sC[tid] = acc;
    }
    __syncthreads();

    // ---- segment table: y = slope*x + intercept, indexed by upper_bound ----
    if (tid == 0) {
        sSeg[0]  = make_float2(0.0f, sC[0]);
        sSeg[KS] = make_float2(0.0f, sC[KS - 1]);
    } else {
        float e0 = sE[tid - 1], e1 = sE[tid];
        float c0 = sC[tid - 1], c1 = sC[tid];
        float sl = (c1 - c0) / (e1 - e0);
        float bi = fmaf(-sl, e0, c0);
        sSeg[tid] = make_float2(sl, bi);
    }
    __syncthreads();                               // sC dead

    // ---- direct bin table ----
    {
        constexpr int BPT = MB / 256;
        const float h = 1.0f / (float)MB;
        int m0 = tid * BPT;
        float v0 = (float)m0 * h;
        int lo = 0, hi = KS;
        while (lo < hi) {
            int mid = (lo + hi) >> 1;
            if (sE[mid] <= v0) lo = mid + 1; else hi = mid;
        }
        int j = lo;
        #pragma unroll
        for (int t = 0; t < BPT; ++t) {
            int m = m0 + t;
            float vn = (float)(m + 1) * h;
            int jn = j;
            while (jn < KS && sE[jn] <= vn) ++jn;
            int c = jn - j;
            float2 e;
            if (c == 0) {
                e = sSeg[j];
            } else {
                e.x = __uint_as_float(SENTINEL);
                e.y = __uint_as_float((unsigned)j | ((unsigned)c << 9));
            }
            sBin[m] = e;
            j = jn;
        }
    }
    __syncthreads();

    // ---- streaming loop: depth-2 register pipeline over groups of 4 float4 ----
    const float4* __restrict__ in4 = (const float4*)(hdr + (size_t)b * NPIX_PER_B);
    float4*                   out4 = (float4*)(out + (size_t)b * NPIX_PER_B);

    const int S  = gridDim.x * blockDim.x;
    const int i0 = blockIdx.x * blockDim.x + tid;

    const int n   = (NP4 - 1 - i0) / S + 1;
    const int G   = n >> 2;
    const int rem = n & 3;

    if (G > 0) {
        int idx = i0;
        float4 na = in4[idx];
        float4 nb = in4[idx + S];
        float4 nc = in4[idx + 2 * S];
        float4 nd = in4[idx + 3 * S];

        for (int g = 0; g < G; ++g) {
            float4 ca = na, cb = nb, cc = nc, cd = nd;
            int nidx = idx + 4 * S;

            {   // clamped prefetch of group g+1 (last one discarded, harmless)
                int a0 = nidx;             a0 = (a0 < NP4) ? a0 : (NP4 - 1);
                int a1 = nidx + S;         a1 = (a1 < NP4) ? a1 : (NP4 - 1);
                int a2 = nidx + 2 * S;     a2 = (a2 < NP4) ? a2 : (NP4 - 1);
                int a3 = nidx + 3 * S;     a3 = (a3 < NP4) ? a3 : (NP4 - 1);
                na = in4[a0];
                nb = in4[a1];
                nc = in4[a2];
                nd = in4[a3];
            }

            store4<NT>(&out4[idx],         interp_vec<MB, NT>(ca, sE, sSeg, sBin));
            store4<NT>(&out4[idx + S],     interp_vec<MB, NT>(cb, sE, sSeg, sBin));
            store4<NT>(&out4[idx + 2 * S], interp_vec<MB, NT>(cc, sE, sSeg, sBin));
            store4<NT>(&out4[idx + 3 * S], interp_vec<MB, NT>(cd, sE, sSeg, sBin));

            idx = nidx;
        }
        for (int t = 0; t < rem; ++t) {
            int a = idx + t * S;
            float4 p = in4[a];
            store4<NT>(&out4[a], interp_vec<MB, NT>(p, sE, sSeg, sBin));
        }
    } else {
        for (int a = i0; a < NP4; a += S) {
            float4 p = in4[a];
            store4<NT>(&out4[a], interp_vec<MB, NT>(p, sE, sSeg, sBin));
        }
    }
}

// ---- distinct names so rocprof rows separate the three variants ----
__global__ __launch_bounds__(256, 8)
void tmo_ctrl_nt2048(const float* __restrict__ hdr, const float* __restrict__ w,
                     const float* __restrict__ E,   const float* __restrict__ f0,
                     const float* __restrict__ Hb,  float* __restrict__ out)
{
    tmo_body<2048, true>(hdr, w, E, f0, Hb, out);
}

__global__ __launch_bounds__(256, 8)
void tmo_plain2048(const float* __restrict__ hdr, const float* __restrict__ w,
                   const float* __restrict__ E,   const float* __restrict__ f0,
                   const float* __restrict__ Hb,  float* __restrict__ out)
{
    tmo_body<2048, false>(hdr, w, E, f0, Hb, out);
}

__global__ __launch_bounds__(256, 8)
void tmo_nt1024(const float* __restrict__ hdr, const float* __restrict__ w,
                const float* __restrict__ E,   const float* __restrict__ f0,
                const float* __restrict__ Hb,  float* __restrict__ out)
{
    tmo_body<1024, true>(hdr, w, E, f0, Hb, out);
}

extern "C" void kernel_launch(void* const* d_in, const int* in_sizes, int n_in,
                              void* d_out, int out_size, void* d_ws, size_t ws_size,
                              hipStream_t stream)
{
    const float* hdr = (const float*)d_in[0];  // [8,3,1080,1920]
    const float* w   = (const float*)d_in[1];  // [8,25]
    const float* E   = (const float*)d_in[2];  // [256] sorted
    const float* f0  = (const float*)d_in[3];  // [256]
    const float* Hb  = (const float*)d_in[4];  // [256,25]
    float* out = (float*)d_out;

    dim3 block(256, 1, 1);

    // batches 0-2: control (NT, M=2048). 682*3 = 2046 blocks ~ 8/CU.
    tmo_ctrl_nt2048<<<dim3(682, 3, 1), block, 0, stream>>>(hdr, w, E, f0, Hb, out);

    // batches 3-5: plain stores (vmcnt/NT-retirement probe)
    tmo_plain2048<<<dim3(682, 3, 1), block, 0, stream>>>(
        hdr + (size_t)3 * NPIX_PER_B, w + 3 * NB, E, f0, Hb,
        out + (size_t)3 * NPIX_PER_B);

    // batches 6-7: M=1024, 11.2KB LDS (occupancy probe). 1024*2 = 2048 blocks.
    tmo_nt1024<<<dim3(1024, 2, 1), block, 0, stream>>>(
        hdr + (size_t)6 * NPIX_PER_B, w + 6 * NB, E, f0, Hb,
        out + (size_t)6 * NPIX_PER_B);
}

// Round 6
// 348.473 us; speedup vs baseline: 1.0704x; 1.0704x over previous
//
#include <hip/hip_runtime.h>

// DifferentiableTMO: per-batch piecewise-linear CRF LUT over 8x3x1080x1920 fp32.
// HBM floor: ~300MB real traffic @6.6TB/s ~= 45-60us (fill kernels measured
// 6.64-6.77 TB/s pure-write at 9.8% occupancy -> BW needs no occupancy).
// R6 (resubmit; R5 bench was an infra timeout, kernel never measured):
//     PLAIN STORES (drop nontemporal). Surviving theory after R3 (LDS removal:
//     neutral), R4 (source reorder: compiler re-sank, neutral), R5 (fill-kernel
//     evidence): NT stores bypass L2 so their ack returns from the HBM write
//     queue; vmcnt is a single IN-ORDER counter shared by loads+stores, so
//     every iteration's load-consume s_waitcnt transitively waits on the
//     previous NT store's HBM retirement (~600-1000cy) -> ~65% idle, nothing
//     saturated. Plain stores ack from L2 (~100cy), decoupling the chain.
//     Single dispatch, all 8 batches, otherwise IDENTICAL to the 131.8us
//     control for a clean A/B.

#define KS 256          // CRF sample points
#define NB 25           // PCA basis curves
#define M_BINS 2048     // bucket bins over [0,1)
#define BINS_PER_THR (M_BINS / 256)   // 8
#define NPIX_PER_B 6220800            // 3*1080*1920
#define NP4 (NPIX_PER_B / 4)          // 1555200 float4 per batch

#define SENTINEL 0xFFFFFFFFu          // negative NaN; real slopes are finite

__device__ __forceinline__ float interp_one(float x,
                                            const float* __restrict__ sE,
                                            const float2* __restrict__ sSeg,
                                            const float2* __restrict__ sBin)
{
    // x in [0,1): m = floor(x*2048) exact (x*2^11 is an exponent shift)
    int m = (int)(x * (float)M_BINS);
    m = (m > M_BINS - 1) ? (M_BINS - 1) : m;
    float2 sg = sBin[m];               // single ds_read_b64 on the common path
    if (__builtin_expect(__float_as_uint(sg.x) == SENTINEL, 0)) {
        unsigned int pk = __float_as_uint(sg.y);
        unsigned int j  = pk & 0x1FFu;     // upper_bound(E, bin_start)
        unsigned int c  = pk >> 9;         // breakpoints inside this bin
        while (c) {
            if (sE[j] > x) break;
            ++j; --c;
        }
        sg = sSeg[j];
    }
    float y = fmaf(sg.x, x, sg.y);
    return fminf(fmaxf(y, 0.0f), 1.0f);
}

__device__ __forceinline__ float4 interp_vec(float4 p,
                                             const float* __restrict__ sE,
                                             const float2* __restrict__ sSeg,
                                             const float2* __restrict__ sBin)
{
    float4 r;
    r.x = interp_one(p.x, sE, sSeg, sBin);
    r.y = interp_one(p.y, sE, sSeg, sBin);
    r.z = interp_one(p.z, sE, sSeg, sBin);
    r.w = interp_one(p.w, sE, sSeg, sBin);
    return r;
}

__global__ __launch_bounds__(256, 8)
void tmo_lut_kernel(const float* __restrict__ hdr,
                    const float* __restrict__ w,
                    const float* __restrict__ E,
                    const float* __restrict__ f0,
                    const float* __restrict__ Hb,
                    float* __restrict__ out)
{
    __shared__ float  sE[KS];                     // 1 KB
    __shared__ float2 sSeg[KS + 1];               // 2056 B
    __shared__ float2 sBin[M_BINS];               // 16 KB

    float* sC = (float*)sBin;                     // overlay: dead after sSeg built

    const int tid = threadIdx.x;
    const int b   = blockIdx.y;

    // ---- stage E, per-batch curve ----
    sE[tid] = E[tid];
    {
        float acc = f0[tid];
        const float* wb = w + b * NB;   // block-uniform -> scalar loads
        const float* hb = Hb + tid * NB;
        #pragma unroll
        for (int n = 0; n < NB; ++n) acc = fmaf(hb[n], wb[n], acc);
        sC[tid] = acc;
    }
    __syncthreads();

    // ---- segment table: y = slope*x + intercept, indexed by upper_bound ----
    if (tid == 0) {
        sSeg[0]  = make_float2(0.0f, sC[0]);
        sSeg[KS] = make_float2(0.0f, sC[KS - 1]);
    } else {
        float e0 = sE[tid - 1], e1 = sE[tid];
        float c0 = sC[tid - 1], c1 = sC[tid];
        float sl = (c1 - c0) / (e1 - e0);
        float bi = fmaf(-sl, e0, c0);
        sSeg[tid] = make_float2(sl, bi);
    }
    __syncthreads();                               // sC dead after this point

    // ---- direct bin table ----
    {
        const float h = 1.0f / (float)M_BINS;
        int m0 = tid * BINS_PER_THR;
        float v0 = (float)m0 * h;
        int lo = 0, hi = KS;
        while (lo < hi) {
            int mid = (lo + hi) >> 1;
            if (sE[mid] <= v0) lo = mid + 1; else hi = mid;
        }
        int j = lo;
        #pragma unroll
        for (int t = 0; t < BINS_PER_THR; ++t) {
            int m = m0 + t;
            float vn = (float)(m + 1) * h;
            int jn = j;
            while (jn < KS && sE[jn] <= vn) ++jn;
            int c = jn - j;
            float2 e;
            if (c == 0) {
                e = sSeg[j];
            } else {
                e.x = __uint_as_float(SENTINEL);
                e.y = __uint_as_float((unsigned)j | ((unsigned)c << 9));
            }
            sBin[m] = e;
            j = jn;
        }
    }
    __syncthreads();

    // ---- streaming loop: groups of 4 float4, PLAIN stores ----
    const float4* __restrict__ in4 = (const float4*)(hdr + (size_t)b * NPIX_PER_B);
    float4*                   out4 = (float4*)(out + (size_t)b * NPIX_PER_B);

    const int S  = gridDim.x * blockDim.x;         // 65536
    const int i0 = blockIdx.x * blockDim.x + tid;

    const int n   = (NP4 - 1 - i0) / S + 1;        // 23 or 24
    const int G   = n >> 2;                        // full groups of 4
    const int rem = n & 3;                         // 0..3 leftover

    if (G > 0) {
        int idx = i0;
        float4 na = in4[idx];
        float4 nb = in4[idx + S];
        float4 nc = in4[idx + 2 * S];
        float4 nd = in4[idx + 3 * S];

        for (int g = 0; g < G; ++g) {
            float4 ca = na, cb = nb, cc = nc, cd = nd;
            int nidx = idx + 4 * S;

            {   // clamped prefetch of group g+1 (last one discarded, harmless)
                int a0 = nidx;             a0 = (a0 < NP4) ? a0 : (NP4 - 1);
                int a1 = nidx + S;         a1 = (a1 < NP4) ? a1 : (NP4 - 1);
                int a2 = nidx + 2 * S;     a2 = (a2 < NP4) ? a2 : (NP4 - 1);
                int a3 = nidx + 3 * S;     a3 = (a3 < NP4) ? a3 : (NP4 - 1);
                na = in4[a0];
                nb = in4[a1];
                nc = in4[a2];
                nd = in4[a3];
            }

            out4[idx]         = interp_vec(ca, sE, sSeg, sBin);
            out4[idx + S]     = interp_vec(cb, sE, sSeg, sBin);
            out4[idx + 2 * S] = interp_vec(cc, sE, sSeg, sBin);
            out4[idx + 3 * S] = interp_vec(cd, sE, sSeg, sBin);

            idx = nidx;
        }
        for (int t = 0; t < rem; ++t) {
            int a = idx + t * S;
            float4 p = in4[a];
            out4[a] = interp_vec(p, sE, sSeg, sBin);
        }
    } else {
        for (int a = i0; a < NP4; a += S) {
            float4 p = in4[a];
            out4[a] = interp_vec(p, sE, sSeg, sBin);
        }
    }
}

extern "C" void kernel_launch(void* const* d_in, const int* in_sizes, int n_in,
                              void* d_out, int out_size, void* d_ws, size_t ws_size,
                              hipStream_t stream)
{
    const float* hdr = (const float*)d_in[0];  // [8,3,1080,1920]
    const float* w   = (const float*)d_in[1];  // [8,25]
    const float* E   = (const float*)d_in[2];  // [256] sorted
    const float* f0  = (const float*)d_in[3];  // [256]
    const float* Hb  = (const float*)d_in[4];  // [256,25]
    float* out = (float*)d_out;

    dim3 grid(256, 8, 1);   // 2048 blocks = 8 blocks/CU on 256 CUs
    dim3 block(256, 1, 1);
    tmo_lut_kernel<<<grid, block, 0, stream>>>(hdr, w, E, f0, Hb, out);
}